// Round 18
// baseline (121.854 us; speedup 1.0000x reference)
//
#include <hip/hip_runtime.h>
#include <hip/hip_fp16.h>

// Problem constants (from reference) — ALL TENSORS ARE FLOAT32.
#define B_    1024
#define N_    256
#define E_    2304
#define FIN_  6
#define VEC_  26
#define HSTR_ 40        // f16 LDS row stride (80 B, 16B-aligned)
#define NT_   512       // threads per block: 2 per node

typedef _Float16 half8 __attribute__((ext_vector_type(8)));
typedef float    f32x4 __attribute__((ext_vector_type(4)));

// butterfly pair-sum: add partner lane's (lane^1) half2 value
__device__ __forceinline__ __half2 pairsum(__half2 v) {
    union { __half2 h; int i; } u; u.h = v;
    int p = __shfl_xor(u.i, 1, 64);
    union { int i; __half2 h; } w; w.i = p;
    return __hfma2(w.h, __floats2half2_rn(1.f, 1.f), v);
}

// ---------------------------------------------------------------------------
// One block per batch element; 512 threads = 2 per node (sub = t&1).
// Gather: edges split across the pair, shfl_xor combine. GEMM L2/L3: MFMA
// 16x16x32 f16, 8 waves x 32-node slabs. CSR build per block (wave scans).
// ---------------------------------------------------------------------------
__global__ __launch_bounds__(512) void fused_kernel(
    const float* __restrict__ gf,    // [B,N,6]
    const float* __restrict__ vec,   // [B,26]
    const int* __restrict__ src, const int* __restrict__ dst,
    const float* __restrict__ W1, const float* __restrict__ b1,   // [6,32],[32]
    const float* __restrict__ W2, const float* __restrict__ b2,   // [32,32]
    const float* __restrict__ W3, const float* __restrict__ b3,
    const float* __restrict__ We, const float* __restrict__ be,   // [32,32]
    const float* __restrict__ Wpi, const float* __restrict__ bpi, // [58,512],[512]
    const float* __restrict__ Wvf, const float* __restrict__ bvf,
    float* __restrict__ out)         // f32; pi @ [0,524288), vf @ +524288
{
    __shared__ __align__(16) __half hbuf[N_ * HSTR_];   // 20,480 B
    __shared__ unsigned int packedE[E_];                //  9,216 B
    __shared__ float part[16 * 33];
    __shared__ float hgl[32];
    __shared__ float comb[VEC_ + 32];
    __shared__ int   wsum[4];

    const int t = threadIdx.x;
    const int b = blockIdx.x;
    const int lane = t & 63, wv = t >> 6;   // wv 0..7
    const int sub = t & 1;

    // ---- CSR scratch overlaid on hbuf (consumed before feature staging) ----
    int*   deg_o  = (int*)hbuf;          // [256]
    int*   deg_i  = (int*)hbuf + 256;    // [256]
    int*   scanA  = (int*)hbuf + 512;    // [256]
    int*   cursor = (int*)hbuf + 768;    // [256]
    int*   perm   = (int*)hbuf + 1024;   // [256]
    float* inv_o  = (float*)hbuf + 1280; // [256]
    float* inv_i  = (float*)hbuf + 1536; // [256]
    int*   bcnt   = (int*)hbuf + 1792;   // [64]
    int*   boff   = (int*)hbuf + 1856;   // [64]

    // A. zero
    if (t < 256) { deg_o[t] = 0; deg_i[t] = 0; }
    if (t < 64) bcnt[t] = 0;
    __syncthreads();

    // B. degree count (all 512 threads)
    for (int e = t; e < E_; e += NT_) {
        atomicAdd(&deg_o[src[e]], 1);
        atomicAdd(&deg_i[dst[e]], 1);
    }
    __syncthreads();

    // C. inv factors + wave scan of deg_i (threads 0..255 = waves 0..3)
    int x = 0, dI = 0, bucket = 0;
    if (t < 256) {
        dI = deg_i[t];
        int dO = deg_o[t];
        inv_o[t] = dO > 0 ? rsqrtf((float)dO) : 0.f;
        inv_i[t] = dI > 0 ? rsqrtf((float)dI) : 0.f;
        x = dI;
#pragma unroll
        for (int d = 1; d < 64; d <<= 1) {
            int y = __shfl_up(x, d, 64);
            if (lane >= d) x += y;
        }
        if (lane == 63) wsum[wv] = x;
        bucket = dI > 63 ? 63 : dI;
        atomicAdd(&bcnt[bucket], 1);
    }
    __syncthreads();

    // D. combine wave sums; bucket-offset scan
    if (t < 256) {
        int prefix = 0;
#pragma unroll
        for (int w = 0; w < 3; ++w) if (w < wv) prefix += wsum[w];
        int incl = x + prefix;
        scanA[t]  = incl;
        cursor[t] = incl - dI;
    }
    if (t < 64) {
        int c = bcnt[t], xx = c;
#pragma unroll
        for (int d = 1; d < 64; d <<= 1) {
            int y = __shfl_up(xx, d, 64);
            if (lane >= d) xx += y;
        }
        boff[t] = xx - c;   // exclusive
    }
    __syncthreads();

    // E. perm scatter (t<256) + edge scatter (all threads, re-read src/dst)
    if (t < 256) { int pos = atomicAdd(&boff[bucket], 1); perm[pos] = t; }
    for (int e = t; e < E_; e += NT_) {
        int s = src[e], dd = dst[e];
        int pos = atomicAdd(&cursor[dd], 1);
        float nrm = inv_o[s] * inv_i[dd];
        unsigned short h = __half_as_ushort(__float2half(nrm));
        packedE[pos] = ((unsigned int)s << 16) | (unsigned int)h;
    }
    __syncthreads();

    // F. node assignment (pairs share a node); then overlay is dead
    const int node = perm[t >> 1];
    const int end  = scanA[node];
    const int beg  = end - deg_i[node];
    __syncthreads();

    // G. stage node features as f16 (cols 6,7 zero-padded)
    {
        const float* g = gf + (size_t)b * (N_ * FIN_);
        for (int i = t; i < N_ * 8; i += NT_) {
            int n = i >> 3, k = i & 7;
            hbuf[n * HSTR_ + k] = __float2half((k < FIN_) ? g[n * FIN_ + k] : 0.f);
        }
    }
    __syncthreads();

    const __half2 z2 = __float2half2_rn(0.f);

    // ---- layer 1: split gather + pair-combine + even-lane f32 [6x32] GEMM ----
    {
        __half2 a2[4] = {z2, z2, z2, z2};
        for (int e = beg + sub; e < end; e += 2) {
            unsigned int u = packedE[e];
            __half2 w2 = __half2half2(__ushort_as_half((unsigned short)(u & 0xffffu)));
            union { float4 f4; __half2 h2[4]; } r;
            r.f4 = *(const float4*)&hbuf[(u >> 16) * HSTR_];
#pragma unroll
            for (int q = 0; q < 4; ++q) a2[q] = __hfma2(w2, r.h2[q], a2[q]);
        }
#pragma unroll
        for (int q = 0; q < 4; ++q) a2[q] = pairsum(a2[q]);

        float o[32];
        if (sub == 0) {
            float a[FIN_];
#pragma unroll
            for (int k = 0; k < FIN_; ++k)
                a[k] = (k & 1) ? __high2float(a2[k >> 1]) : __low2float(a2[k >> 1]);
#pragma unroll
            for (int j = 0; j < 32; ++j) o[j] = b1[j];
#pragma unroll
            for (int k = 0; k < FIN_; ++k) {
                float ak = a[k];
                const float* wr = &W1[k * 32];
#pragma unroll
                for (int j = 0; j < 32; ++j) o[j] += ak * wr[j];
            }
        }
        __syncthreads();
        if (sub == 0) {
            union { float4 f4; __half2 h2[4]; } w;
            float4* row = (float4*)&hbuf[node * HSTR_];
#pragma unroll
            for (int q = 0; q < 4; ++q) {
#pragma unroll
                for (int r = 0; r < 4; ++r)
                    w.h2[r] = __floats2half2_rn(fmaxf(o[8*q + 2*r], 0.f), fmaxf(o[8*q + 2*r + 1], 0.f));
                row[q] = w.f4;
            }
        }
    }
    __syncthreads();

    // ---- layers 2 & 3: split gather + pair-combine + MFMA (32-node slabs) ----
    const int m16  = lane & 15;
    const int q4   = lane >> 4;
    const int slab = wv * 32;          // 8 waves x 32 nodes

    for (int L = 0; L < 2; ++L) {
        const float* Wl = (L == 0) ? W2 : W3;
        const float* Bl = (L == 0) ? b2 : b3;

        // B fragments + bias (global vector loads, overlap with gather)
        half8 bfrag[2];
        float bias_c[2];
#pragma unroll
        for (int h = 0; h < 2; ++h) {
            int col = m16 + 16 * h;
#pragma unroll
            for (int j = 0; j < 8; ++j)
                bfrag[h][j] = (_Float16)Wl[(q4 * 8 + j) * 32 + col];
            bias_c[h] = Bl[col];
        }

        // gather (edges split across pair)
        __half2 acc2[16];
#pragma unroll
        for (int j = 0; j < 16; ++j) acc2[j] = z2;
        for (int e = beg + sub; e < end; e += 2) {
            unsigned int u = packedE[e];
            __half2 w2 = __half2half2(__ushort_as_half((unsigned short)(u & 0xffffu)));
            const float4* hr = (const float4*)&hbuf[(u >> 16) * HSTR_];
            union { float4 f4; __half2 h2[4]; } r0, r1, r2, r3;
            r0.f4 = hr[0]; r1.f4 = hr[1]; r2.f4 = hr[2]; r3.f4 = hr[3];
#pragma unroll
            for (int q = 0; q < 4; ++q) {
                acc2[q]      = __hfma2(w2, r0.h2[q], acc2[q]);
                acc2[4 + q]  = __hfma2(w2, r1.h2[q], acc2[4 + q]);
                acc2[8 + q]  = __hfma2(w2, r2.h2[q], acc2[8 + q]);
                acc2[12 + q] = __hfma2(w2, r3.h2[q], acc2[12 + q]);
            }
        }
#pragma unroll
        for (int j = 0; j < 16; ++j) acc2[j] = pairsum(acc2[j]);
        __syncthreads();                     // all gather reads of h done
        if (sub == 0) {
            // stage agg rows (h is dead)
            union { float4 f4; __half2 h2[4]; } w;
            float4* row = (float4*)&hbuf[node * HSTR_];
#pragma unroll
            for (int q = 0; q < 4; ++q) {
#pragma unroll
                for (int r = 0; r < 4; ++r) w.h2[r] = acc2[4 * q + r];
                row[q] = w.f4;
            }
        }
        __syncthreads();                     // agg visible

        // A fragments: wave's own 32-node slab, M=32 -> 2 MFMA row-groups
        half8 afrag[2];
#pragma unroll
        for (int g = 0; g < 2; ++g) {
            union { float4 f4; half8 h8; } u;
            u.f4 = *(const float4*)&hbuf[(slab + g * 16 + m16) * HSTR_ + q4 * 8];
            afrag[g] = u.h8;
        }
        f32x4 D[2][2];
#pragma unroll
        for (int g = 0; g < 2; ++g) {
#pragma unroll
            for (int h = 0; h < 2; ++h) {
                f32x4 c = {bias_c[h], bias_c[h], bias_c[h], bias_c[h]};
                D[g][h] = __builtin_amdgcn_mfma_f32_16x16x32_f16(afrag[g], bfrag[h], c, 0, 0, 0);
            }
        }
#pragma unroll
        for (int g = 0; g < 2; ++g) {
#pragma unroll
            for (int h = 0; h < 2; ++h) {
#pragma unroll
                for (int r = 0; r < 4; ++r) {
                    float v = fmaxf(D[g][h][r], 0.f);
                    hbuf[(slab + g * 16 + q4 * 4 + r) * HSTR_ + h * 16 + m16] = __float2half(v);
                }
            }
        }
        __syncthreads();
    }

    // ---- mean over nodes -> hg[32] (f32) ----
    {
        int j = t & 31, g16 = t >> 5;        // 16 groups x 16 nodes
        float s = 0.f;
        for (int i = 0; i < 16; ++i)
            s += __half2float(hbuf[(g16 * 16 + i) * HSTR_ + j]);
        part[g16 * 33 + j] = s;
    }
    __syncthreads();
    if (t < 32) {
        float sum = 0.f;
#pragma unroll
        for (int g16 = 0; g16 < 16; ++g16) sum += part[g16 * 33 + t];
        hgl[t] = sum * (1.0f / 256.0f);
    }
    __syncthreads();

    // ---- emb + comb (f32) ----
    if (t < 32) {
        float v = be[t];
#pragma unroll
        for (int j = 0; j < 32; ++j) v += hgl[j] * We[j * 32 + t];
        comb[VEC_ + t] = v;
    }
    if (t < VEC_) comb[t] = vec[b * VEC_ + t];
    __syncthreads();

    // ---- head: thread t -> pi[t], vf[t] (f32) ----
    {
        float p = bpi[t], v = bvf[t];
        for (int k = 0; k < VEC_ + 32; ++k) {
            float c = comb[k];
            p += c * Wpi[k * 512 + t];
            v += c * Wvf[k * 512 + t];
        }
        out[(size_t)b * 512 + t]          = fmaxf(p, 0.f);
        out[524288 + (size_t)b * 512 + t] = fmaxf(v, 0.f);
    }
}

extern "C" void kernel_launch(void* const* d_in, const int* in_sizes, int n_in,
                              void* d_out, int out_size, void* d_ws, size_t ws_size,
                              hipStream_t stream)
{
    // d_in order: 0 gf, 1 vec, 2 src, 3 dst, 4 W1, 5 b1, 6 W2, 7 b2, 8 W3, 9 b3,
    //             10 W_emb, 11 b_emb, 12 W_pi, 13 b_pi, 14 W_vf, 15 b_vf
    fused_kernel<<<B_, NT_, 0, stream>>>(
        (const float*)d_in[0], (const float*)d_in[1],
        (const int*)d_in[2], (const int*)d_in[3],
        (const float*)d_in[4], (const float*)d_in[5],
        (const float*)d_in[6], (const float*)d_in[7],
        (const float*)d_in[8], (const float*)d_in[9],
        (const float*)d_in[10], (const float*)d_in[11],
        (const float*)d_in[12], (const float*)d_in[13],
        (const float*)d_in[14], (const float*)d_in[15],
        (float*)d_out);
}

// Round 19
// 121.015 us; speedup vs baseline: 1.0069x; 1.0069x over previous
//
#include <hip/hip_runtime.h>
#include <hip/hip_fp16.h>

// Problem constants (from reference) — ALL TENSORS ARE FLOAT32.
#define B_    1024
#define N_    256
#define E_    2304
#define FIN_  6
#define VEC_  26
#define HSTR_ 40        // f16 LDS row stride (80 B, 16B-aligned)
#define NT_   512       // threads per block: 2 per node
#define EPT_  5         // max edges per thread in CSR build (ceil(2304/512))

typedef _Float16 half8 __attribute__((ext_vector_type(8)));
typedef float    f32x4 __attribute__((ext_vector_type(4)));

// butterfly pair-sum: add partner lane's (lane^1) half2 value
__device__ __forceinline__ __half2 pairsum(__half2 v) {
    union { __half2 h; int i; } u; u.h = v;
    int p = __shfl_xor(u.i, 1, 64);
    union { int i; __half2 h; } w; w.i = p;
    return __hfma2(w.h, __floats2half2_rn(1.f, 1.f), v);
}

// ---------------------------------------------------------------------------
// One block per batch element; 512 threads = 2 per node (sub = t&1).
// Gather: edges split across the pair, shfl_xor combine. GEMM L2/L3: MFMA
// 16x16x32 f16, 8 waves x 32-node slabs. CSR build per block (wave scans,
// single-pass edge load). Layer-1 GEMM pair-split (no idle lanes).
// ---------------------------------------------------------------------------
__global__ __launch_bounds__(512) void fused_kernel(
    const float* __restrict__ gf,    // [B,N,6]
    const float* __restrict__ vec,   // [B,26]
    const int* __restrict__ src, const int* __restrict__ dst,
    const float* __restrict__ W1, const float* __restrict__ b1,   // [6,32],[32]
    const float* __restrict__ W2, const float* __restrict__ b2,   // [32,32]
    const float* __restrict__ W3, const float* __restrict__ b3,
    const float* __restrict__ We, const float* __restrict__ be,   // [32,32]
    const float* __restrict__ Wpi, const float* __restrict__ bpi, // [58,512],[512]
    const float* __restrict__ Wvf, const float* __restrict__ bvf,
    float* __restrict__ out)         // f32; pi @ [0,524288), vf @ +524288
{
    __shared__ __align__(16) __half hbuf[N_ * HSTR_];   // 20,480 B
    __shared__ unsigned int packedE[E_];                //  9,216 B
    __shared__ float part[16 * 33];
    __shared__ float hgl[32];
    __shared__ float comb[VEC_ + 32];
    __shared__ int   wsum[4];

    const int t = threadIdx.x;
    const int b = blockIdx.x;
    const int lane = t & 63, wv = t >> 6;   // wv 0..7
    const int sub = t & 1;

    // ---- CSR scratch overlaid on hbuf (consumed before feature staging) ----
    int*   deg_o  = (int*)hbuf;          // [256]
    int*   deg_i  = (int*)hbuf + 256;    // [256]
    int*   scanA  = (int*)hbuf + 512;    // [256]
    int*   cursor = (int*)hbuf + 768;    // [256]
    int*   perm   = (int*)hbuf + 1024;   // [256]
    float* inv_o  = (float*)hbuf + 1280; // [256]
    float* inv_i  = (float*)hbuf + 1536; // [256]
    int*   bcnt   = (int*)hbuf + 1792;   // [64]
    int*   boff   = (int*)hbuf + 1856;   // [64]

    // A. zero
    if (t < 256) { deg_o[t] = 0; deg_i[t] = 0; }
    if (t < 64) bcnt[t] = 0;
    __syncthreads();

    // B. load edges ONCE into registers; count degrees
    int sB[EPT_], dB[EPT_];
#pragma unroll
    for (int i = 0; i < EPT_; ++i) {
        int e = t + NT_ * i;
        if (e < E_) { sB[i] = src[e]; dB[i] = dst[e]; }
        else        { sB[i] = -1;     dB[i] = -1; }
    }
#pragma unroll
    for (int i = 0; i < EPT_; ++i)
        if (sB[i] >= 0) { atomicAdd(&deg_o[sB[i]], 1); atomicAdd(&deg_i[dB[i]], 1); }
    __syncthreads();

    // C. inv factors + wave scan of deg_i (threads 0..255 = waves 0..3)
    int x = 0, dI = 0, bucket = 0;
    if (t < 256) {
        dI = deg_i[t];
        int dO = deg_o[t];
        inv_o[t] = dO > 0 ? rsqrtf((float)dO) : 0.f;
        inv_i[t] = dI > 0 ? rsqrtf((float)dI) : 0.f;
        x = dI;
#pragma unroll
        for (int d = 1; d < 64; d <<= 1) {
            int y = __shfl_up(x, d, 64);
            if (lane >= d) x += y;
        }
        if (lane == 63) wsum[wv] = x;
        bucket = dI > 63 ? 63 : dI;
        atomicAdd(&bcnt[bucket], 1);
    }
    __syncthreads();

    // D. combine wave sums; bucket-offset scan
    if (t < 256) {
        int prefix = 0;
#pragma unroll
        for (int w = 0; w < 3; ++w) if (w < wv) prefix += wsum[w];
        int incl = x + prefix;
        scanA[t]  = incl;
        cursor[t] = incl - dI;
    }
    if (t < 64) {
        int c = bcnt[t], xx = c;
#pragma unroll
        for (int d = 1; d < 64; d <<= 1) {
            int y = __shfl_up(xx, d, 64);
            if (lane >= d) xx += y;
        }
        boff[t] = xx - c;   // exclusive
    }
    __syncthreads();

    // E. perm scatter (t<256) + edge scatter (register-cached edges)
    if (t < 256) { int pos = atomicAdd(&boff[bucket], 1); perm[pos] = t; }
#pragma unroll
    for (int i = 0; i < EPT_; ++i) {
        if (sB[i] >= 0) {
            int s = sB[i], dd = dB[i];
            int pos = atomicAdd(&cursor[dd], 1);
            float nrm = inv_o[s] * inv_i[dd];
            unsigned short h = __half_as_ushort(__float2half(nrm));
            packedE[pos] = ((unsigned int)s << 16) | (unsigned int)h;
        }
    }
    __syncthreads();

    // F. node assignment (pairs share a node); then overlay is dead
    const int node = perm[t >> 1];
    const int end  = scanA[node];
    const int beg  = end - deg_i[node];
    __syncthreads();

    // G. stage node features as f16 (cols 6,7 zero-padded)
    {
        const float* g = gf + (size_t)b * (N_ * FIN_);
        for (int i = t; i < N_ * 8; i += NT_) {
            int n = i >> 3, k = i & 7;
            hbuf[n * HSTR_ + k] = __float2half((k < FIN_) ? g[n * FIN_ + k] : 0.f);
        }
    }
    __syncthreads();

    const __half2 z2 = __float2half2_rn(0.f);

    // ---- layer 1: split gather + pair-combine + pair-split f32 [6x32] GEMM ----
    {
        __half2 a2[4] = {z2, z2, z2, z2};
        for (int e = beg + sub; e < end; e += 2) {
            unsigned int u = packedE[e];
            __half2 w2 = __half2half2(__ushort_as_half((unsigned short)(u & 0xffffu)));
            union { float4 f4; __half2 h2[4]; } r;
            r.f4 = *(const float4*)&hbuf[(u >> 16) * HSTR_];
#pragma unroll
            for (int q = 0; q < 4; ++q) a2[q] = __hfma2(w2, r.h2[q], a2[q]);
        }
#pragma unroll
        for (int q = 0; q < 4; ++q) a2[q] = pairsum(a2[q]);

        // both lanes hold full a[6]; each sub computes 16 of the 32 outputs
        float a[FIN_], o[16];
        const int j0 = sub * 16;
#pragma unroll
        for (int k = 0; k < FIN_; ++k)
            a[k] = (k & 1) ? __high2float(a2[k >> 1]) : __low2float(a2[k >> 1]);
#pragma unroll
        for (int j = 0; j < 16; ++j) o[j] = b1[j0 + j];
#pragma unroll
        for (int k = 0; k < FIN_; ++k) {
            float ak = a[k];
            const float* wr = &W1[k * 32 + j0];
#pragma unroll
            for (int j = 0; j < 16; ++j) o[j] += ak * wr[j];
        }
        __syncthreads();
        {
            union { float4 f4; __half2 h2[4]; } w0, w1;
#pragma unroll
            for (int r = 0; r < 4; ++r) {
                w0.h2[r] = __floats2half2_rn(fmaxf(o[2*r], 0.f),     fmaxf(o[2*r+1], 0.f));
                w1.h2[r] = __floats2half2_rn(fmaxf(o[8+2*r], 0.f),   fmaxf(o[8+2*r+1], 0.f));
            }
            float4* row = (float4*)&hbuf[node * HSTR_ + j0];
            row[0] = w0.f4; row[1] = w1.f4;
        }
    }
    __syncthreads();

    // ---- layers 2 & 3: split gather + pair-combine + MFMA (32-node slabs) ----
    const int m16  = lane & 15;
    const int q4   = lane >> 4;
    const int slab = wv * 32;          // 8 waves x 32 nodes

    for (int L = 0; L < 2; ++L) {
        const float* Wl = (L == 0) ? W2 : W3;
        const float* Bl = (L == 0) ? b2 : b3;

        // B fragments + bias (global vector loads, overlap with gather)
        half8 bfrag[2];
        float bias_c[2];
#pragma unroll
        for (int h = 0; h < 2; ++h) {
            int col = m16 + 16 * h;
#pragma unroll
            for (int j = 0; j < 8; ++j)
                bfrag[h][j] = (_Float16)Wl[(q4 * 8 + j) * 32 + col];
            bias_c[h] = Bl[col];
        }

        // gather (edges split across pair)
        __half2 acc2[16];
#pragma unroll
        for (int j = 0; j < 16; ++j) acc2[j] = z2;
        for (int e = beg + sub; e < end; e += 2) {
            unsigned int u = packedE[e];
            __half2 w2 = __half2half2(__ushort_as_half((unsigned short)(u & 0xffffu)));
            const float4* hr = (const float4*)&hbuf[(u >> 16) * HSTR_];
            union { float4 f4; __half2 h2[4]; } r0, r1, r2, r3;
            r0.f4 = hr[0]; r1.f4 = hr[1]; r2.f4 = hr[2]; r3.f4 = hr[3];
#pragma unroll
            for (int q = 0; q < 4; ++q) {
                acc2[q]      = __hfma2(w2, r0.h2[q], acc2[q]);
                acc2[4 + q]  = __hfma2(w2, r1.h2[q], acc2[4 + q]);
                acc2[8 + q]  = __hfma2(w2, r2.h2[q], acc2[8 + q]);
                acc2[12 + q] = __hfma2(w2, r3.h2[q], acc2[12 + q]);
            }
        }
#pragma unroll
        for (int j = 0; j < 16; ++j) acc2[j] = pairsum(acc2[j]);
        __syncthreads();                     // all gather reads of h done
        if (sub == 0) {
            // stage agg rows (h is dead)
            union { float4 f4; __half2 h2[4]; } w;
            float4* row = (float4*)&hbuf[node * HSTR_];
#pragma unroll
            for (int q = 0; q < 4; ++q) {
#pragma unroll
                for (int r = 0; r < 4; ++r) w.h2[r] = acc2[4 * q + r];
                row[q] = w.f4;
            }
        }
        __syncthreads();                     // agg visible

        // A fragments: wave's own 32-node slab, M=32 -> 2 MFMA row-groups
        half8 afrag[2];
#pragma unroll
        for (int g = 0; g < 2; ++g) {
            union { float4 f4; half8 h8; } u;
            u.f4 = *(const float4*)&hbuf[(slab + g * 16 + m16) * HSTR_ + q4 * 8];
            afrag[g] = u.h8;
        }
        f32x4 D[2][2];
#pragma unroll
        for (int g = 0; g < 2; ++g) {
#pragma unroll
            for (int h = 0; h < 2; ++h) {
                f32x4 c = {bias_c[h], bias_c[h], bias_c[h], bias_c[h]};
                D[g][h] = __builtin_amdgcn_mfma_f32_16x16x32_f16(afrag[g], bfrag[h], c, 0, 0, 0);
            }
        }
#pragma unroll
        for (int g = 0; g < 2; ++g) {
#pragma unroll
            for (int h = 0; h < 2; ++h) {
#pragma unroll
                for (int r = 0; r < 4; ++r) {
                    float v = fmaxf(D[g][h][r], 0.f);
                    hbuf[(slab + g * 16 + q4 * 4 + r) * HSTR_ + h * 16 + m16] = __float2half(v);
                }
            }
        }
        __syncthreads();
    }

    // ---- mean over nodes -> hg[32] (f32) ----
    {
        int j = t & 31, g16 = t >> 5;        // 16 groups x 16 nodes
        float s = 0.f;
        for (int i = 0; i < 16; ++i)
            s += __half2float(hbuf[(g16 * 16 + i) * HSTR_ + j]);
        part[g16 * 33 + j] = s;
    }
    __syncthreads();
    if (t < 32) {
        float sum = 0.f;
#pragma unroll
        for (int g16 = 0; g16 < 16; ++g16) sum += part[g16 * 33 + t];
        hgl[t] = sum * (1.0f / 256.0f);
    }
    __syncthreads();

    // ---- emb + comb (f32) ----
    if (t < 32) {
        float v = be[t];
#pragma unroll
        for (int j = 0; j < 32; ++j) v += hgl[j] * We[j * 32 + t];
        comb[VEC_ + t] = v;
    }
    if (t < VEC_) comb[t] = vec[b * VEC_ + t];
    __syncthreads();

    // ---- head: thread t -> pi[t], vf[t] (f32) ----
    {
        float p = bpi[t], v = bvf[t];
        for (int k = 0; k < VEC_ + 32; ++k) {
            float c = comb[k];
            p += c * Wpi[k * 512 + t];
            v += c * Wvf[k * 512 + t];
        }
        out[(size_t)b * 512 + t]          = fmaxf(p, 0.f);
        out[524288 + (size_t)b * 512 + t] = fmaxf(v, 0.f);
    }
}

extern "C" void kernel_launch(void* const* d_in, const int* in_sizes, int n_in,
                              void* d_out, int out_size, void* d_ws, size_t ws_size,
                              hipStream_t stream)
{
    // d_in order: 0 gf, 1 vec, 2 src, 3 dst, 4 W1, 5 b1, 6 W2, 7 b2, 8 W3, 9 b3,
    //             10 W_emb, 11 b_emb, 12 W_pi, 13 b_pi, 14 W_vf, 15 b_vf
    fused_kernel<<<B_, NT_, 0, stream>>>(
        (const float*)d_in[0], (const float*)d_in[1],
        (const int*)d_in[2], (const int*)d_in[3],
        (const float*)d_in[4], (const float*)d_in[5],
        (const float*)d_in[6], (const float*)d_in[7],
        (const float*)d_in[8], (const float*)d_in[9],
        (const float*)d_in[10], (const float*)d_in[11],
        (const float*)d_in[12], (const float*)d_in[13],
        (const float*)d_in[14], (const float*)d_in[15],
        (float*)d_out);
}